// Round 1
// baseline (2477.643 us; speedup 1.0000x reference)
//
#include <hip/hip_runtime.h>
#include <hip/hip_cooperative_groups.h>

namespace cg = cooperative_groups;

#define N_    64
#define W_    512
#define H_    512
#define S_    513
#define TWOH_ 1024
#define KS_   8

__device__ __forceinline__ float tanh_fast(float x) {
  float xc = fminf(fmaxf(x, -15.0f), 15.0f);
  float e = __expf(2.0f * xc);
  return (e - 1.0f) / (e + 1.0f);
}
__device__ __forceinline__ float sigmoid_f(float x) {
  return 1.0f / (1.0f + __expf(-x));
}
__device__ __forceinline__ float wred_sum(float v) {
#pragma unroll
  for (int m = 32; m > 0; m >>= 1) v += __shfl_xor(v, m, 64);
  return v;
}

// ---------------------------------------------------------------------------
// Vc[r][h] = dot(A[r,:], B[h,:])   A: (32768,1024) = context rows, B: V_w (512,1024)
// 64x64 tile, BK=32, 4x4 per thread, fp32 vector ALU.
// ---------------------------------------------------------------------------
__global__ __launch_bounds__(256) void vgemm_f32(const float* __restrict__ A,
                                                 const float* __restrict__ B,
                                                 float* __restrict__ C) {
  __shared__ float As[32][68];
  __shared__ float Bs[32][68];
  int bx = blockIdx.x;  // 0..7   (h tiles)
  int by = blockIdx.y;  // 0..511 (row tiles)
  int t = threadIdx.x;
  int tr = t >> 4, tc = t & 15;
  int arow = t >> 3;        // 0..31
  int acol = (t & 7) << 2;  // 0,4,..,28
  const float* Ab = A + (size_t)(by * 64) * 1024;
  const float* Bb = B + (size_t)(bx * 64) * 1024;
  float acc[4][4] = {};
  for (int k0 = 0; k0 < 1024; k0 += 32) {
    float4 a0 = *(const float4*)(Ab + (size_t)arow * 1024 + k0 + acol);
    float4 a1 = *(const float4*)(Ab + (size_t)(arow + 32) * 1024 + k0 + acol);
    float4 b0 = *(const float4*)(Bb + (size_t)arow * 1024 + k0 + acol);
    float4 b1 = *(const float4*)(Bb + (size_t)(arow + 32) * 1024 + k0 + acol);
    __syncthreads();
    As[acol + 0][arow] = a0.x; As[acol + 1][arow] = a0.y;
    As[acol + 2][arow] = a0.z; As[acol + 3][arow] = a0.w;
    As[acol + 0][arow + 32] = a1.x; As[acol + 1][arow + 32] = a1.y;
    As[acol + 2][arow + 32] = a1.z; As[acol + 3][arow + 32] = a1.w;
    Bs[acol + 0][arow] = b0.x; Bs[acol + 1][arow] = b0.y;
    Bs[acol + 2][arow] = b0.z; Bs[acol + 3][arow] = b0.w;
    Bs[acol + 0][arow + 32] = b1.x; Bs[acol + 1][arow + 32] = b1.y;
    Bs[acol + 2][arow + 32] = b1.z; Bs[acol + 3][arow + 32] = b1.w;
    __syncthreads();
#pragma unroll
    for (int kk = 0; kk < 32; ++kk) {
      const float4 a4 = *(const float4*)(&As[kk][tr * 4]);
      const float4 b4 = *(const float4*)(&Bs[kk][tc * 4]);
      acc[0][0] += a4.x * b4.x; acc[0][1] += a4.x * b4.y; acc[0][2] += a4.x * b4.z; acc[0][3] += a4.x * b4.w;
      acc[1][0] += a4.y * b4.x; acc[1][1] += a4.y * b4.y; acc[1][2] += a4.y * b4.z; acc[1][3] += a4.y * b4.w;
      acc[2][0] += a4.z * b4.x; acc[2][1] += a4.z * b4.y; acc[2][2] += a4.z * b4.z; acc[2][3] += a4.z * b4.w;
      acc[3][0] += a4.w * b4.x; acc[3][1] += a4.w * b4.y; acc[3][2] += a4.w * b4.z; acc[3][3] += a4.w * b4.w;
    }
  }
  int row0 = by * 64 + tr * 4;
  int col0 = bx * 64 + tc * 4;
#pragma unroll
  for (int i = 0; i < 4; ++i) {
    *(float4*)(C + (size_t)(row0 + i) * 512 + col0) =
        make_float4(acc[i][0], acc[i][1], acc[i][2], acc[i][3]);
  }
}

// ---------------------------------------------------------------------------
// Cooperative kernel: prep (masked scores, M0, Cmask) + 8 decode steps.
// 256 blocks x 256 threads. Block b owns j/h pair {2b, 2b+1}; its GRU weight
// rows + W_w rows live in LDS for the whole kernel.
// ---------------------------------------------------------------------------
__global__ __launch_bounds__(256, 1) void pointer_steps(
    const float* __restrict__ ctx, const int* __restrict__ slens,
    const float* __restrict__ Vw, const float* __restrict__ Ww,
    const float* __restrict__ vvec, const float* __restrict__ wih,
    const float* __restrict__ whh, const float* __restrict__ bih,
    const float* __restrict__ bhh, const float* __restrict__ Vc,
    float* __restrict__ scores, float* __restrict__ M0,
    float* __restrict__ Cmask, float* __restrict__ hbuf,
    float* __restrict__ hWb, float* __restrict__ alignedb,
    float* __restrict__ out) {
  cg::grid_group grid = cg::this_grid();
  __shared__ float ls_wih[6][TWOH_];  // rows (jl,gate): gi weights
  __shared__ float ls_whh[6][H_];     // gh weights
  __shared__ float ls_Ww[2][H_];      // W_w rows for owned h pair
  __shared__ float ls_v[H_];
  __shared__ float ls_beta[S_];
  __shared__ float ls_red[256];

  const int b = blockIdx.x;  // 0..255
  const int t = threadIdx.x;
  const int j0 = 2 * b;

  // ---- prologue: persist weights in LDS, zero h[0] ----
  for (int i = t; i < 6 * TWOH_; i += 256) {
    int row = i / TWOH_, d = i - row * TWOH_;
    int jl = row / 3, g = row - jl * 3;
    ls_wih[row][d] = wih[(size_t)(g * H_ + j0 + jl) * TWOH_ + d];
  }
  for (int i = t; i < 6 * H_; i += 256) {
    int row = i / H_, d = i - row * H_;
    int jl = row / 3, g = row - jl * 3;
    ls_whh[row][d] = whh[(size_t)(g * H_ + j0 + jl) * H_ + d];
  }
  for (int i = t; i < 2 * H_; i += 256) {
    int hl = i / H_, d = i - hl * H_;
    ls_Ww[hl][d] = Ww[(size_t)(j0 + hl) * H_ + d];
  }
  for (int i = t; i < H_; i += 256) ls_v[i] = vvec[i];
  if (t < 128) {
    int n = t & 63, jl = t >> 6;
    hbuf[n * H_ + j0 + jl] = 0.0f;
  }
  grid.sync();

  // ---- prep1: masked-position scores (step-invariant) + M0[n] ----
  if (b < N_) {
    int n = b;
    int len = slens[n];
    int w = t >> 6, lane = t & 63;
    int hb = lane << 3;
    float4 v0 = *(const float4*)(&ls_v[hb]);
    float4 v1 = *(const float4*)(&ls_v[hb + 4]);
    float vv[8] = {v0.x, v0.y, v0.z, v0.w, v1.x, v1.y, v1.z, v1.w};
    float mymax = -3.0e38f;
    for (int s = len + 1 + w; s < W_; s += 4) {
      const float* vr = Vc + ((size_t)n * W_ + s) * H_ + hb;
      float4 x0 = *(const float4*)vr;
      float4 x1 = *(const float4*)(vr + 4);
      float xs[8] = {x0.x, x0.y, x0.z, x0.w, x1.x, x1.y, x1.z, x1.w};
      float acc = 0.0f;
#pragma unroll
      for (int i = 0; i < 8; ++i) {
        float vcv = xs[i];
        if (fabsf(vcv) < 1e-5f) {  // near-zero dot: fp64 fix-up for true sign
          const float* cr = ctx + ((size_t)n * W_ + s) * TWOH_;
          const float* wr = Vw + (size_t)(hb + i) * TWOH_;
          double dacc = 0.0;
          for (int d = 0; d < TWOH_; ++d) dacc += (double)cr[d] * (double)wr[d];
          vcv = (dacc > 0.0) ? 1.0f : ((dacc < 0.0) ? -1.0f : 0.0f);
        }
        // f = tanh(-1e10*Vc) = -sign(Vc); score += f * v
        acc += (vcv > 0.0f) ? -vv[i] : ((vcv < 0.0f) ? vv[i] : 0.0f);
      }
      acc = wred_sum(acc);
      if (lane == 0) scores[n * S_ + s] = acc;
      mymax = fmaxf(mymax, acc);
    }
    ls_red[t] = mymax;
    __syncthreads();
    for (int st = 128; st > 0; st >>= 1) {
      if (t < st) ls_red[t] = fmaxf(ls_red[t], ls_red[t + st]);
      __syncthreads();
    }
    if (t == 0) M0[n] = ls_red[0];
  }
  grid.sync();

  // ---- prep2: Cmask[n][d] = sum_masked exp(mscore - M0) * (-1e10 * ctx) ----
  {
    int n = b & 63, dc = b >> 6;
    int len = slens[n];
    int d = dc * 256 + t;
    float m0 = M0[n];
    float acc = 0.0f;
    const float* cb = ctx + (size_t)n * W_ * TWOH_ + d;
#pragma unroll 4
    for (int s = len + 1; s < W_; ++s) {
      float ew = __expf(scores[n * S_ + s] - m0);
      acc += ew * cb[(size_t)s * TWOH_];
    }
    Cmask[n * TWOH_ + d] = acc * (-1.0e10f);
  }
  grid.sync();

  // ---- decode steps ----
  for (int k = 0; k < KS_; ++k) {
    const float* hc = hbuf + (k & 1) * (N_ * H_);
    float* hnx = hbuf + ((k + 1) & 1) * (N_ * H_);

    // P1: hW[n][h] for owned h pair
    if (t < 128) {
      int n = t & 63, hl = t >> 6;
      const float* hr = hc + n * H_;
      const float* wr = ls_Ww[hl];
      float acc = 0.0f;
#pragma unroll 4
      for (int d = 0; d < H_; d += 4) {
        float4 hv = *(const float4*)(hr + d);
        acc += hv.x * wr[d] + hv.y * wr[d + 1] + hv.z * wr[d + 2] + hv.w * wr[d + 3];
      }
      hWb[n * H_ + j0 + hl] = acc;
    }
    grid.sync();

    // P2: valid-position scores (block = (n, s-chunk); wave per row)
    {
      int n = b & 63, c = b >> 6;
      int len = slens[n];
      int smax = min(len, W_ - 1);
      int w = t >> 6, lane = t & 63;
      int hb = lane << 3;
      float4 h0 = *(const float4*)(hWb + n * H_ + hb);
      float4 h1 = *(const float4*)(hWb + n * H_ + hb + 4);
      float4 v0 = *(const float4*)(&ls_v[hb]);
      float4 v1 = *(const float4*)(&ls_v[hb + 4]);
      int s_end = min((c + 1) * 128, smax + 1);
      for (int s = c * 128 + w; s < s_end; s += 4) {
        const float* vr = Vc + ((size_t)n * W_ + s) * H_ + hb;
        float4 x0 = *(const float4*)vr;
        float4 x1 = *(const float4*)(vr + 4);
        float acc;
        acc  = tanh_fast(x0.x + h0.x) * v0.x;
        acc += tanh_fast(x0.y + h0.y) * v0.y;
        acc += tanh_fast(x0.z + h0.z) * v0.z;
        acc += tanh_fast(x0.w + h0.w) * v0.w;
        acc += tanh_fast(x1.x + h1.x) * v1.x;
        acc += tanh_fast(x1.y + h1.y) * v1.y;
        acc += tanh_fast(x1.z + h1.z) * v1.z;
        acc += tanh_fast(x1.w + h1.w) * v1.w;
        acc = wred_sum(acc);
        if (lane == 0) scores[n * S_ + s] = acc;
      }
      if (c == 0 && w == 0) {  // appended zero row: score = sum tanh(hW)*v
        float acc;
        acc  = tanh_fast(h0.x) * v0.x;
        acc += tanh_fast(h0.y) * v0.y;
        acc += tanh_fast(h0.z) * v0.z;
        acc += tanh_fast(h0.w) * v0.w;
        acc += tanh_fast(h1.x) * v1.x;
        acc += tanh_fast(h1.y) * v1.y;
        acc += tanh_fast(h1.z) * v1.z;
        acc += tanh_fast(h1.w) * v1.w;
        acc = wred_sum(acc);
        if (lane == 0) scores[n * S_ + W_] = acc;
      }
    }
    grid.sync();

    // P3: softmax, beta output, aligned
    {
      int n = b & 63, dc = b >> 6;
      int len = slens[n];
      int smax = min(len, W_ - 1);
      float m = -3.0e38f;
      for (int i = t; i < S_; i += 256) m = fmaxf(m, scores[n * S_ + i]);
      ls_red[t] = m;
      __syncthreads();
      for (int st = 128; st > 0; st >>= 1) {
        if (t < st) ls_red[t] = fmaxf(ls_red[t], ls_red[t + st]);
        __syncthreads();
      }
      float M = ls_red[0];
      __syncthreads();
      float dsum = 0.0f;
      for (int i = t; i < S_; i += 256) dsum += __expf(scores[n * S_ + i] - M);
      ls_red[t] = dsum;
      __syncthreads();
      for (int st = 128; st > 0; st >>= 1) {
        if (t < st) ls_red[t] += ls_red[t + st];
        __syncthreads();
      }
      float D = ls_red[0];
      __syncthreads();
      for (int i = t; i < S_; i += 256)
        ls_beta[i] = __expf(scores[n * S_ + i] - M) / D;
      __syncthreads();
      if (dc == 0) {
        float* op = out + (size_t)(n * KS_ + k) * S_;
        for (int i = t; i < S_; i += 256) op[i] = ls_beta[i];
      }
      float coef = __expf(M0[n] - M) / D;
      int d = dc * 256 + t;
      const float* cb = ctx + (size_t)n * W_ * TWOH_ + d;
      float acc = coef * Cmask[n * TWOH_ + d];
#pragma unroll 4
      for (int s = 0; s <= smax; ++s) acc += ls_beta[s] * cb[(size_t)s * TWOH_];
      alignedb[n * TWOH_ + d] = acc;
    }
    grid.sync();

    // P4: GRU cell, j-partitioned (weights already in LDS)
    if (t < 128) {
      int n = t & 63, jl = t >> 6;
      int j = j0 + jl;
      const float* ar = alignedb + n * TWOH_;
      const float* hrow = hc + n * H_;
      const float* w0 = ls_wih[jl * 3 + 0];
      const float* w1 = ls_wih[jl * 3 + 1];
      const float* w2 = ls_wih[jl * 3 + 2];
      float gr = 0.0f, gz = 0.0f, gn = 0.0f;
#pragma unroll 4
      for (int d = 0; d < TWOH_; d += 4) {
        float4 av = *(const float4*)(ar + d);
        gr += av.x * w0[d] + av.y * w0[d + 1] + av.z * w0[d + 2] + av.w * w0[d + 3];
        gz += av.x * w1[d] + av.y * w1[d + 1] + av.z * w1[d + 2] + av.w * w1[d + 3];
        gn += av.x * w2[d] + av.y * w2[d + 1] + av.z * w2[d + 2] + av.w * w2[d + 3];
      }
      const float* u0 = ls_whh[jl * 3 + 0];
      const float* u1 = ls_whh[jl * 3 + 1];
      const float* u2 = ls_whh[jl * 3 + 2];
      float hrd = 0.0f, hzd = 0.0f, hnd = 0.0f;
#pragma unroll 4
      for (int d = 0; d < H_; d += 4) {
        float4 hv = *(const float4*)(hrow + d);
        hrd += hv.x * u0[d] + hv.y * u0[d + 1] + hv.z * u0[d + 2] + hv.w * u0[d + 3];
        hzd += hv.x * u1[d] + hv.y * u1[d + 1] + hv.z * u1[d + 2] + hv.w * u1[d + 3];
        hnd += hv.x * u2[d] + hv.y * u2[d + 1] + hv.z * u2[d + 2] + hv.w * u2[d + 3];
      }
      float irv = gr + bih[j];
      float hrv = hrd + bhh[j];
      float izv = gz + bih[H_ + j];
      float hzv = hzd + bhh[H_ + j];
      float inv = gn + bih[2 * H_ + j];
      float hnv = hnd + bhh[2 * H_ + j];
      float r = sigmoid_f(irv + hrv);
      float z = sigmoid_f(izv + hzv);
      float nc = tanh_fast(inv + r * hnv);
      hnx[n * H_ + j] = (1.0f - z) * nc + z * hrow[j];
    }
    grid.sync();
  }
}

extern "C" void kernel_launch(void* const* d_in, const int* in_sizes, int n_in,
                              void* d_out, int out_size, void* d_ws, size_t ws_size,
                              hipStream_t stream) {
  const float* ctx = (const float*)d_in[0];
  const int* slens = (const int*)d_in[1];
  // d_in[2] = pointer_answers: only its shape (K=8) matters
  const float* Vw = (const float*)d_in[3];
  const float* Ww = (const float*)d_in[4];
  const float* vvec = (const float*)d_in[5];
  const float* wih = (const float*)d_in[6];
  const float* whh = (const float*)d_in[7];
  const float* bih = (const float*)d_in[8];
  const float* bhh = (const float*)d_in[9];
  float* out = (float*)d_out;

  float* ws = (float*)d_ws;
  float* Vc = ws;                                   // 64*512*512
  float* scores = Vc + (size_t)N_ * W_ * H_;        // 64*513
  float* M0v = scores + N_ * S_;                    // 64
  float* Cm = M0v + N_;                             // 64*1024
  float* hb = Cm + N_ * TWOH_;                      // 2*64*512
  float* hWb = hb + 2 * N_ * H_;                    // 64*512
  float* al = hWb + N_ * H_;                        // 64*1024

  vgemm_f32<<<dim3(8, 512), 256, 0, stream>>>(ctx, Vw, Vc);

  void* args[] = {(void*)&ctx, (void*)&slens, (void*)&Vw,  (void*)&Ww,
                  (void*)&vvec, (void*)&wih,  (void*)&whh, (void*)&bih,
                  (void*)&bhh,  (void*)&Vc,   (void*)&scores, (void*)&M0v,
                  (void*)&Cm,   (void*)&hb,   (void*)&hWb, (void*)&al,
                  (void*)&out};
  hipLaunchCooperativeKernel((void*)pointer_steps, dim3(256), dim3(256), args,
                             0, stream);
}

// Round 2
// 2156.909 us; speedup vs baseline: 1.1487x; 1.1487x over previous
//
#include <hip/hip_runtime.h>
#include <hip/hip_cooperative_groups.h>

namespace cg = cooperative_groups;

#define N_    64
#define W_    512
#define H_    512
#define S_    513
#define TWOH_ 1024
#define KS_   8

__device__ __forceinline__ float tanh_fast(float x) {
  float xc = fminf(fmaxf(x, -15.0f), 15.0f);
  float e = __expf(2.0f * xc);
  return (e - 1.0f) / (e + 1.0f);
}
__device__ __forceinline__ float sigmoid_f(float x) {
  return 1.0f / (1.0f + __expf(-x));
}
__device__ __forceinline__ float wred_sum(float v) {
#pragma unroll
  for (int m = 32; m > 0; m >>= 1) v += __shfl_xor(v, m, 64);
  return v;
}

// ---------------------------------------------------------------------------
// Vc[r][h] = dot(A[r,:], B[h,:])   A: (32768,1024), B: V_w (512,1024)
// ---------------------------------------------------------------------------
__global__ __launch_bounds__(256) void vgemm_f32(const float* __restrict__ A,
                                                 const float* __restrict__ B,
                                                 float* __restrict__ C) {
  __shared__ float As[32][68];
  __shared__ float Bs[32][68];
  int bx = blockIdx.x;  // 0..7   (h tiles)
  int by = blockIdx.y;  // 0..511 (row tiles)
  int t = threadIdx.x;
  int tr = t >> 4, tc = t & 15;
  int arow = t >> 3;        // 0..31
  int acol = (t & 7) << 2;  // 0,4,..,28
  const float* Ab = A + (size_t)(by * 64) * 1024;
  const float* Bb = B + (size_t)(bx * 64) * 1024;
  float acc[4][4] = {};
  for (int k0 = 0; k0 < 1024; k0 += 32) {
    float4 a0 = *(const float4*)(Ab + (size_t)arow * 1024 + k0 + acol);
    float4 a1 = *(const float4*)(Ab + (size_t)(arow + 32) * 1024 + k0 + acol);
    float4 b0 = *(const float4*)(Bb + (size_t)arow * 1024 + k0 + acol);
    float4 b1 = *(const float4*)(Bb + (size_t)(arow + 32) * 1024 + k0 + acol);
    __syncthreads();
    As[acol + 0][arow] = a0.x; As[acol + 1][arow] = a0.y;
    As[acol + 2][arow] = a0.z; As[acol + 3][arow] = a0.w;
    As[acol + 0][arow + 32] = a1.x; As[acol + 1][arow + 32] = a1.y;
    As[acol + 2][arow + 32] = a1.z; As[acol + 3][arow + 32] = a1.w;
    Bs[acol + 0][arow] = b0.x; Bs[acol + 1][arow] = b0.y;
    Bs[acol + 2][arow] = b0.z; Bs[acol + 3][arow] = b0.w;
    Bs[acol + 0][arow + 32] = b1.x; Bs[acol + 1][arow + 32] = b1.y;
    Bs[acol + 2][arow + 32] = b1.z; Bs[acol + 3][arow + 32] = b1.w;
    __syncthreads();
#pragma unroll
    for (int kk = 0; kk < 32; ++kk) {
      const float4 a4 = *(const float4*)(&As[kk][tr * 4]);
      const float4 b4 = *(const float4*)(&Bs[kk][tc * 4]);
      acc[0][0] += a4.x * b4.x; acc[0][1] += a4.x * b4.y; acc[0][2] += a4.x * b4.z; acc[0][3] += a4.x * b4.w;
      acc[1][0] += a4.y * b4.x; acc[1][1] += a4.y * b4.y; acc[1][2] += a4.y * b4.z; acc[1][3] += a4.y * b4.w;
      acc[2][0] += a4.z * b4.x; acc[2][1] += a4.z * b4.y; acc[2][2] += a4.z * b4.z; acc[2][3] += a4.z * b4.w;
      acc[3][0] += a4.w * b4.x; acc[3][1] += a4.w * b4.y; acc[3][2] += a4.w * b4.z; acc[3][3] += a4.w * b4.w;
    }
  }
  int row0 = by * 64 + tr * 4;
  int col0 = bx * 64 + tc * 4;
#pragma unroll
  for (int i = 0; i < 4; ++i) {
    *(float4*)(C + (size_t)(row0 + i) * 512 + col0) =
        make_float4(acc[i][0], acc[i][1], acc[i][2], acc[i][3]);
  }
}

// ---------------------------------------------------------------------------
// Cooperative kernel: 256 blocks x 1024 threads (16 waves/CU).
// All phases use full thread count; 60KB dynamic LDS aliased per phase.
// ---------------------------------------------------------------------------
__global__ __launch_bounds__(1024, 4) void pointer_steps(
    const float* __restrict__ ctx, const int* __restrict__ slens,
    const float* __restrict__ Vw, const float* __restrict__ Ww,
    const float* __restrict__ vvec, const float* __restrict__ wih,
    const float* __restrict__ whh, const float* __restrict__ bih,
    const float* __restrict__ bhh, const float* __restrict__ Vc,
    float* __restrict__ scores, float* __restrict__ M0,
    float* __restrict__ Cmask, float* __restrict__ hbuf,
    float* __restrict__ hWb, float* __restrict__ alignedb,
    float* __restrict__ out) {
  cg::grid_group grid = cg::this_grid();
  extern __shared__ float sm[];

  const int b = blockIdx.x;   // 0..255
  const int t = threadIdx.x;  // 0..1023
  const int nb = b & 63;      // batch row for (n, chunk) phases
  const int cb = b >> 6;      // chunk 0..3

  // ---- prologue: zero h[0] ----
  {
    int gid = b * 1024 + t;
    if (gid < N_ * H_) hbuf[gid] = 0.0f;
  }
  grid.sync();

  // ---- prep1: masked-position scores (step-invariant) + M0[n] ----
  if (b < N_) {
    int n = b;
    int len = slens[n];
    int w = t >> 6, lane = t & 63;
    int hb = lane << 3;
    float4 v0 = *(const float4*)(vvec + hb);
    float4 v1 = *(const float4*)(vvec + hb + 4);
    float vv[8] = {v0.x, v0.y, v0.z, v0.w, v1.x, v1.y, v1.z, v1.w};
    float mymax = -3.0e38f;
    for (int s = len + 1 + w; s < W_; s += 16) {
      const float* vr = Vc + ((size_t)n * W_ + s) * H_ + hb;
      float4 x0 = *(const float4*)vr;
      float4 x1 = *(const float4*)(vr + 4);
      float xs[8] = {x0.x, x0.y, x0.z, x0.w, x1.x, x1.y, x1.z, x1.w};
      float acc = 0.0f;
#pragma unroll
      for (int i = 0; i < 8; ++i) {
        float vcv = xs[i];
        if (fabsf(vcv) < 1e-5f) {  // near-zero dot: fp64 fix-up for true sign
          const float* cr = ctx + ((size_t)n * W_ + s) * TWOH_;
          const float* wr = Vw + (size_t)(hb + i) * TWOH_;
          double dacc = 0.0;
          for (int d = 0; d < TWOH_; ++d) dacc += (double)cr[d] * (double)wr[d];
          vcv = (dacc > 0.0) ? 1.0f : ((dacc < 0.0) ? -1.0f : 0.0f);
        }
        acc += (vcv > 0.0f) ? -vv[i] : ((vcv < 0.0f) ? vv[i] : 0.0f);
      }
      acc = wred_sum(acc);
      if (lane == 0) scores[n * S_ + s] = acc;
      mymax = fmaxf(mymax, acc);
    }
    sm[t] = mymax;
    __syncthreads();
    for (int st = 512; st > 0; st >>= 1) {
      if (t < st) sm[t] = fmaxf(sm[t], sm[t + st]);
      __syncthreads();
    }
    if (t == 0) M0[n] = sm[0];
  }
  grid.sync();

  // ---- prep2: Cmask[n][d] = sum_masked exp(mscore - M0) * (-1e10 * ctx) ----
  {
    int len = slens[nb];
    float m0 = M0[nb];
    int dl = t & 63, sl = t >> 6;  // 64 d-groups x 16 s-slices
    int d4 = cb * 256 + dl * 4;
    const float4* cp = (const float4*)(ctx + (size_t)nb * W_ * TWOH_) + (d4 >> 2);
    float4 acc = make_float4(0.f, 0.f, 0.f, 0.f);
#pragma unroll 4
    for (int s = len + 1 + sl; s < W_; s += 16) {
      float ew = __expf(scores[nb * S_ + s] - m0);
      float4 c4 = cp[(size_t)s * (TWOH_ / 4)];
      acc.x += ew * c4.x; acc.y += ew * c4.y;
      acc.z += ew * c4.z; acc.w += ew * c4.w;
    }
    float4* red4 = (float4*)sm;  // [16][64]
    red4[sl * 64 + dl] = acc;
    __syncthreads();
    if (sl == 0) {
      float4 s4 = red4[dl];
#pragma unroll
      for (int i = 1; i < 16; ++i) {
        float4 o = red4[i * 64 + dl];
        s4.x += o.x; s4.y += o.y; s4.z += o.z; s4.w += o.w;
      }
      s4.x *= -1.0e10f; s4.y *= -1.0e10f; s4.z *= -1.0e10f; s4.w *= -1.0e10f;
      *(float4*)(Cmask + nb * TWOH_ + d4) = s4;
    }
  }
  grid.sync();

  // ---- decode steps ----
  for (int k = 0; k < KS_; ++k) {
    const float* hc = hbuf + (k & 1) * (N_ * H_);
    float* hnx = hbuf + ((k + 1) & 1) * (N_ * H_);

    // PA: hW[n, cb*128 .. +128)  (slice-parallel dots, LDS reduce)
    {
      int hl = t & 127, sl = t >> 7;  // 128 outputs x 8 d-slices of 64
      const float* wr = Ww + (size_t)(cb * 128 + hl) * H_ + sl * 64;
      const float* hr = hc + nb * H_ + sl * 64;
      float a = 0.0f;
#pragma unroll
      for (int i = 0; i < 64; i += 4) {
        float4 h4 = *(const float4*)(hr + i);
        float4 w4 = *(const float4*)(wr + i);
        a += h4.x * w4.x + h4.y * w4.y + h4.z * w4.z + h4.w * w4.w;
      }
      sm[sl * 128 + hl] = a;
      __syncthreads();
      if (sl == 0) {
        float s = sm[hl];
#pragma unroll
        for (int i = 1; i < 8; ++i) s += sm[i * 128 + hl];
        hWb[nb * H_ + cb * 128 + hl] = s;
      }
    }
    grid.sync();

    // PB: valid-position scores; wave per position, 16 waves
    {
      int len = slens[nb];
      int smax = min(len, W_ - 1);
      int w = t >> 6, lane = t & 63;
      int hb = lane << 3;
      float4 h0 = *(const float4*)(hWb + nb * H_ + hb);
      float4 h1 = *(const float4*)(hWb + nb * H_ + hb + 4);
      float4 v0 = *(const float4*)(vvec + hb);
      float4 v1 = *(const float4*)(vvec + hb + 4);
      int s_end = min((cb + 1) * 128 - 1, smax);
      for (int s = cb * 128 + w; s <= s_end; s += 16) {
        const float* vr = Vc + ((size_t)nb * W_ + s) * H_ + hb;
        float4 x0 = *(const float4*)vr;
        float4 x1 = *(const float4*)(vr + 4);
        float acc;
        acc  = tanh_fast(x0.x + h0.x) * v0.x;
        acc += tanh_fast(x0.y + h0.y) * v0.y;
        acc += tanh_fast(x0.z + h0.z) * v0.z;
        acc += tanh_fast(x0.w + h0.w) * v0.w;
        acc += tanh_fast(x1.x + h1.x) * v1.x;
        acc += tanh_fast(x1.y + h1.y) * v1.y;
        acc += tanh_fast(x1.z + h1.z) * v1.z;
        acc += tanh_fast(x1.w + h1.w) * v1.w;
        acc = wred_sum(acc);
        if (lane == 0) scores[nb * S_ + s] = acc;
      }
      if (cb == 3 && w == 15) {  // appended zero row
        float acc;
        acc  = tanh_fast(h0.x) * v0.x;
        acc += tanh_fast(h0.y) * v0.y;
        acc += tanh_fast(h0.z) * v0.z;
        acc += tanh_fast(h0.w) * v0.w;
        acc += tanh_fast(h1.x) * v1.x;
        acc += tanh_fast(h1.y) * v1.y;
        acc += tanh_fast(h1.z) * v1.z;
        acc += tanh_fast(h1.w) * v1.w;
        acc = wred_sum(acc);
        if (lane == 0) scores[nb * S_ + W_] = acc;
      }
    }
    grid.sync();

    // PC1: softmax + beta out + aligned d-slice
    {
      int len = slens[nb];
      int smax = min(len, W_ - 1);
      float* beta = sm;         // 513 (pad to 520)
      float* red = sm + 520;    // 1024
      float m = (t < S_) ? scores[nb * S_ + t] : -3.0e38f;
      red[t] = m;
      __syncthreads();
      for (int st = 512; st > 0; st >>= 1) {
        if (t < st) red[t] = fmaxf(red[t], red[t + st]);
        __syncthreads();
      }
      float M = red[0];
      __syncthreads();
      float e = 0.0f;
      if (t < S_) e = __expf(scores[nb * S_ + t] - M);
      red[t] = e;
      __syncthreads();
      for (int st = 512; st > 0; st >>= 1) {
        if (t < st) red[t] += red[t + st];
        __syncthreads();
      }
      float D = red[0];
      __syncthreads();
      if (t < S_) {
        float bt = e / D;
        beta[t] = bt;
        if (cb == 0) out[(size_t)(nb * KS_ + k) * S_ + t] = bt;
      }
      __syncthreads();
      // aligned: d4 = cb*256 + dl*4, 16 s-slices
      int dl = t & 63, sl = t >> 6;
      int d4 = cb * 256 + dl * 4;
      const float4* cp = (const float4*)(ctx + (size_t)nb * W_ * TWOH_) + (d4 >> 2);
      float4 acc = make_float4(0.f, 0.f, 0.f, 0.f);
#pragma unroll 4
      for (int s = sl; s <= smax; s += 16) {
        float bt = beta[s];
        float4 c4 = cp[(size_t)s * (TWOH_ / 4)];
        acc.x += bt * c4.x; acc.y += bt * c4.y;
        acc.z += bt * c4.z; acc.w += bt * c4.w;
      }
      float4* red4 = (float4*)(sm + 1544);  // [16][64]
      red4[sl * 64 + dl] = acc;
      __syncthreads();
      if (sl == 0) {
        float4 s4 = red4[dl];
#pragma unroll
        for (int i = 1; i < 16; ++i) {
          float4 o = red4[i * 64 + dl];
          s4.x += o.x; s4.y += o.y; s4.z += o.z; s4.w += o.w;
        }
        float coef = __expf(M0[nb] - M) / D;
        float4 cm = *(const float4*)(Cmask + nb * TWOH_ + d4);
        s4.x += coef * cm.x; s4.y += coef * cm.y;
        s4.z += coef * cm.z; s4.w += coef * cm.w;
        *(float4*)(alignedb + nb * TWOH_ + d4) = s4;
      }
    }
    grid.sync();

    // PC2: GRU; block owns j0=2b,2b+1; weights staged in LDS; 8 d-slices
    {
      const int j0 = 2 * b;
      float* ls_wih = sm;          // 6*1024
      float* ls_whh = sm + 6144;   // 6*512
      float* part = sm + 9216;     // 8*128*6
      for (int i = t; i < 6 * TWOH_; i += 1024) {
        int row = i >> 10, d = i & 1023;
        int jl = row / 3, g = row - jl * 3;
        ls_wih[i] = wih[(size_t)(g * H_ + j0 + jl) * TWOH_ + d];
      }
      for (int i = t; i < 6 * H_; i += 1024) {
        int row = i >> 9, d = i & 511;
        int jl = row / 3, g = row - jl * 3;
        ls_whh[i] = whh[(size_t)(g * H_ + j0 + jl) * H_ + d];
      }
      __syncthreads();
      int nj = t & 127, sl = t >> 7;  // (n,jl) x 8 slices
      int n = nj & 63, jl = nj >> 6;
      const float* ar = alignedb + n * TWOH_ + sl * 128;
      const float* hr = hc + n * H_ + sl * 64;
      const float* w0 = ls_wih + (jl * 3 + 0) * TWOH_ + sl * 128;
      const float* w1 = ls_wih + (jl * 3 + 1) * TWOH_ + sl * 128;
      const float* w2 = ls_wih + (jl * 3 + 2) * TWOH_ + sl * 128;
      const float* u0 = ls_whh + (jl * 3 + 0) * H_ + sl * 64;
      const float* u1 = ls_whh + (jl * 3 + 1) * H_ + sl * 64;
      const float* u2 = ls_whh + (jl * 3 + 2) * H_ + sl * 64;
      float g0 = 0.f, g1 = 0.f, g2 = 0.f;
#pragma unroll 8
      for (int i = 0; i < 128; i += 4) {
        float4 a4 = *(const float4*)(ar + i);
        g0 += a4.x * w0[i] + a4.y * w0[i + 1] + a4.z * w0[i + 2] + a4.w * w0[i + 3];
        g1 += a4.x * w1[i] + a4.y * w1[i + 1] + a4.z * w1[i + 2] + a4.w * w1[i + 3];
        g2 += a4.x * w2[i] + a4.y * w2[i + 1] + a4.z * w2[i + 2] + a4.w * w2[i + 3];
      }
      float q0 = 0.f, q1 = 0.f, q2 = 0.f;
#pragma unroll 8
      for (int i = 0; i < 64; i += 4) {
        float4 h4 = *(const float4*)(hr + i);
        q0 += h4.x * u0[i] + h4.y * u0[i + 1] + h4.z * u0[i + 2] + h4.w * u0[i + 3];
        q1 += h4.x * u1[i] + h4.y * u1[i + 1] + h4.z * u1[i + 2] + h4.w * u1[i + 3];
        q2 += h4.x * u2[i] + h4.y * u2[i + 1] + h4.z * u2[i + 2] + h4.w * u2[i + 3];
      }
      float* pp = part + (sl * 128 + nj) * 6;
      pp[0] = g0; pp[1] = g1; pp[2] = g2; pp[3] = q0; pp[4] = q1; pp[5] = q2;
      __syncthreads();
      if (t < 128) {
        int n2 = t & 63, jl2 = t >> 6;
        int j = j0 + jl2;
        float G0 = 0.f, G1 = 0.f, G2 = 0.f, Q0 = 0.f, Q1 = 0.f, Q2 = 0.f;
#pragma unroll
        for (int s = 0; s < 8; ++s) {
          float* p = part + (s * 128 + t) * 6;
          G0 += p[0]; G1 += p[1]; G2 += p[2];
          Q0 += p[3]; Q1 += p[4]; Q2 += p[5];
        }
        float r = sigmoid_f(G0 + bih[j] + Q0 + bhh[j]);
        float z = sigmoid_f(G1 + bih[H_ + j] + Q1 + bhh[H_ + j]);
        float nc = tanh_fast(G2 + bih[2 * H_ + j] + r * (Q2 + bhh[2 * H_ + j]));
        hnx[n2 * H_ + j] = (1.0f - z) * nc + z * hc[n2 * H_ + j];
      }
    }
    grid.sync();
  }
}

extern "C" void kernel_launch(void* const* d_in, const int* in_sizes, int n_in,
                              void* d_out, int out_size, void* d_ws, size_t ws_size,
                              hipStream_t stream) {
  const float* ctx = (const float*)d_in[0];
  const int* slens = (const int*)d_in[1];
  const float* Vw = (const float*)d_in[3];
  const float* Ww = (const float*)d_in[4];
  const float* vvec = (const float*)d_in[5];
  const float* wih = (const float*)d_in[6];
  const float* whh = (const float*)d_in[7];
  const float* bih = (const float*)d_in[8];
  const float* bhh = (const float*)d_in[9];
  float* out = (float*)d_out;

  float* ws = (float*)d_ws;
  float* Vc = ws;                                   // 64*512*512
  float* scores = Vc + (size_t)N_ * W_ * H_;        // 64*513
  float* M0v = scores + N_ * S_;                    // 64
  float* Cm = M0v + N_;                             // 64*1024
  float* hb = Cm + N_ * TWOH_;                      // 2*64*512
  float* hWb = hb + 2 * N_ * H_;                    // 64*512
  float* al = hWb + N_ * H_;                        // 64*1024

  vgemm_f32<<<dim3(8, 512), 256, 0, stream>>>(ctx, Vw, Vc);

  void* args[] = {(void*)&ctx, (void*)&slens, (void*)&Vw,  (void*)&Ww,
                  (void*)&vvec, (void*)&wih,  (void*)&whh, (void*)&bih,
                  (void*)&bhh,  (void*)&Vc,   (void*)&scores, (void*)&M0v,
                  (void*)&Cm,   (void*)&hb,   (void*)&hWb, (void*)&al,
                  (void*)&out};
  hipLaunchCooperativeKernel((void*)pointer_steps, dim3(256), dim3(1024), args,
                             61440, stream);
}

// Round 3
// 1087.999 us; speedup vs baseline: 2.2772x; 1.9825x over previous
//
#include <hip/hip_runtime.h>

#define N_    64
#define W_    512
#define H_    512
#define S_    513
#define TWOH_ 1024
#define KS_   8

__device__ __forceinline__ float tanh_fast(float x) {
  float xc = fminf(fmaxf(x, -15.0f), 15.0f);
  float e = __expf(2.0f * xc);
  return (e - 1.0f) / (e + 1.0f);
}
__device__ __forceinline__ float sigmoid_f(float x) {
  return 1.0f / (1.0f + __expf(-x));
}
__device__ __forceinline__ float wred_sum(float v) {
#pragma unroll
  for (int m = 32; m > 0; m >>= 1) v += __shfl_xor(v, m, 64);
  return v;
}

// ---------------------------------------------------------------------------
// Vc[r][h] = dot(A[r,:], B[h,:])   A: (32768,1024), B: V_w (512,1024)
// ---------------------------------------------------------------------------
__global__ __launch_bounds__(256) void vgemm_f32(const float* __restrict__ A,
                                                 const float* __restrict__ B,
                                                 float* __restrict__ C) {
  __shared__ float As[32][68];
  __shared__ float Bs[32][68];
  int bx = blockIdx.x;  // 0..7   (h tiles)
  int by = blockIdx.y;  // 0..511 (row tiles)
  int t = threadIdx.x;
  int tr = t >> 4, tc = t & 15;
  int arow = t >> 3;        // 0..31
  int acol = (t & 7) << 2;  // 0,4,..,28
  const float* Ab = A + (size_t)(by * 64) * 1024;
  const float* Bb = B + (size_t)(bx * 64) * 1024;
  float acc[4][4] = {};
  for (int k0 = 0; k0 < 1024; k0 += 32) {
    float4 a0 = *(const float4*)(Ab + (size_t)arow * 1024 + k0 + acol);
    float4 a1 = *(const float4*)(Ab + (size_t)(arow + 32) * 1024 + k0 + acol);
    float4 b0 = *(const float4*)(Bb + (size_t)arow * 1024 + k0 + acol);
    float4 b1 = *(const float4*)(Bb + (size_t)(arow + 32) * 1024 + k0 + acol);
    __syncthreads();
    As[acol + 0][arow] = a0.x; As[acol + 1][arow] = a0.y;
    As[acol + 2][arow] = a0.z; As[acol + 3][arow] = a0.w;
    As[acol + 0][arow + 32] = a1.x; As[acol + 1][arow + 32] = a1.y;
    As[acol + 2][arow + 32] = a1.z; As[acol + 3][arow + 32] = a1.w;
    Bs[acol + 0][arow] = b0.x; Bs[acol + 1][arow] = b0.y;
    Bs[acol + 2][arow] = b0.z; Bs[acol + 3][arow] = b0.w;
    Bs[acol + 0][arow + 32] = b1.x; Bs[acol + 1][arow + 32] = b1.y;
    Bs[acol + 2][arow + 32] = b1.z; Bs[acol + 3][arow + 32] = b1.w;
    __syncthreads();
#pragma unroll
    for (int kk = 0; kk < 32; ++kk) {
      const float4 a4 = *(const float4*)(&As[kk][tr * 4]);
      const float4 b4 = *(const float4*)(&Bs[kk][tc * 4]);
      acc[0][0] += a4.x * b4.x; acc[0][1] += a4.x * b4.y; acc[0][2] += a4.x * b4.z; acc[0][3] += a4.x * b4.w;
      acc[1][0] += a4.y * b4.x; acc[1][1] += a4.y * b4.y; acc[1][2] += a4.y * b4.z; acc[1][3] += a4.y * b4.w;
      acc[2][0] += a4.z * b4.x; acc[2][1] += a4.z * b4.y; acc[2][2] += a4.z * b4.z; acc[2][3] += a4.z * b4.w;
      acc[3][0] += a4.w * b4.x; acc[3][1] += a4.w * b4.y; acc[3][2] += a4.w * b4.z; acc[3][3] += a4.w * b4.w;
    }
  }
  int row0 = by * 64 + tr * 4;
  int col0 = bx * 64 + tc * 4;
#pragma unroll
  for (int i = 0; i < 4; ++i) {
    *(float4*)(C + (size_t)(row0 + i) * 512 + col0) =
        make_float4(acc[i][0], acc[i][1], acc[i][2], acc[i][3]);
  }
}

// ---------------------------------------------------------------------------
// prep1: masked-position scores (step-invariant) + M0[n].  grid 64 x 1024
// ---------------------------------------------------------------------------
__global__ __launch_bounds__(1024) void k_prep1(
    const float* __restrict__ ctx, const int* __restrict__ slens,
    const float* __restrict__ Vw, const float* __restrict__ vvec,
    const float* __restrict__ Vc, float* __restrict__ scores,
    float* __restrict__ M0) {
  __shared__ float red[1024];
  int n = blockIdx.x;
  int t = threadIdx.x;
  int len = slens[n];
  int w = t >> 6, lane = t & 63;
  int hb = lane << 3;
  float4 v0 = *(const float4*)(vvec + hb);
  float4 v1 = *(const float4*)(vvec + hb + 4);
  float vv[8] = {v0.x, v0.y, v0.z, v0.w, v1.x, v1.y, v1.z, v1.w};
  float mymax = -3.0e38f;
  for (int s = len + 1 + w; s < W_; s += 16) {
    const float* vr = Vc + ((size_t)n * W_ + s) * H_ + hb;
    float4 x0 = *(const float4*)vr;
    float4 x1 = *(const float4*)(vr + 4);
    float xs[8] = {x0.x, x0.y, x0.z, x0.w, x1.x, x1.y, x1.z, x1.w};
    float acc = 0.0f;
#pragma unroll
    for (int i = 0; i < 8; ++i) {
      float vcv = xs[i];
      if (fabsf(vcv) < 1e-5f) {  // near-zero dot: fp64 fix-up for true sign
        const float* cr = ctx + ((size_t)n * W_ + s) * TWOH_;
        const float* wr = Vw + (size_t)(hb + i) * TWOH_;
        double dacc = 0.0;
        for (int d = 0; d < TWOH_; ++d) dacc += (double)cr[d] * (double)wr[d];
        vcv = (dacc > 0.0) ? 1.0f : ((dacc < 0.0) ? -1.0f : 0.0f);
      }
      acc += (vcv > 0.0f) ? -vv[i] : ((vcv < 0.0f) ? vv[i] : 0.0f);
    }
    acc = wred_sum(acc);
    if (lane == 0) scores[n * S_ + s] = acc;
    mymax = fmaxf(mymax, acc);
  }
  red[t] = mymax;
  __syncthreads();
  for (int st = 512; st > 0; st >>= 1) {
    if (t < st) red[t] = fmaxf(red[t], red[t + st]);
    __syncthreads();
  }
  if (t == 0) M0[n] = red[0];
}

// ---------------------------------------------------------------------------
// prep2: Cmask[n][d] = sum_masked exp(ms - M0) * (-1e10*ctx).  grid 256 x 1024
// ---------------------------------------------------------------------------
__global__ __launch_bounds__(1024) void k_prep2(
    const float* __restrict__ ctx, const int* __restrict__ slens,
    const float* __restrict__ scores, const float* __restrict__ M0,
    float* __restrict__ Cmask) {
  __shared__ float4 red4[16 * 64];
  int nb = blockIdx.x & 63, cb = blockIdx.x >> 6;
  int t = threadIdx.x;
  int len = slens[nb];
  float m0 = M0[nb];
  int dl = t & 63, sl = t >> 6;
  int d4 = cb * 256 + dl * 4;
  const float4* cp = (const float4*)(ctx + (size_t)nb * W_ * TWOH_) + (d4 >> 2);
  float4 acc = make_float4(0.f, 0.f, 0.f, 0.f);
#pragma unroll 4
  for (int s = len + 1 + sl; s < W_; s += 16) {
    float ew = __expf(scores[nb * S_ + s] - m0);
    float4 c4 = cp[(size_t)s * (TWOH_ / 4)];
    acc.x += ew * c4.x; acc.y += ew * c4.y;
    acc.z += ew * c4.z; acc.w += ew * c4.w;
  }
  red4[sl * 64 + dl] = acc;
  __syncthreads();
  if (sl == 0) {
    float4 s4 = red4[dl];
#pragma unroll
    for (int i = 1; i < 16; ++i) {
      float4 o = red4[i * 64 + dl];
      s4.x += o.x; s4.y += o.y; s4.z += o.z; s4.w += o.w;
    }
    s4.x *= -1.0e10f; s4.y *= -1.0e10f; s4.z *= -1.0e10f; s4.w *= -1.0e10f;
    *(float4*)(Cmask + nb * TWOH_ + d4) = s4;
  }
}

// ---------------------------------------------------------------------------
// hW[n,h] = dot(h[n,:], Ww[h,:]).  grid 64 x 1024; block owns 8 h rows.
// ---------------------------------------------------------------------------
__global__ __launch_bounds__(1024) void k_hw(const float* __restrict__ hc,
                                             const float* __restrict__ Ww,
                                             float* __restrict__ hWb) {
  __shared__ float ww[8][512];
  int b = blockIdx.x;  // h tile
  int t = threadIdx.x;
  int h0 = b * 8;
  for (int i = t; i < 8 * 512; i += 1024)
    ww[i >> 9][i & 511] = Ww[(size_t)(h0 + (i >> 9)) * H_ + (i & 511)];
  __syncthreads();
  int lane = t & 63;
  int hl = (t >> 6) & 7;
  int nh = t >> 9;  // 0..1
  const float* wr = &ww[hl][lane << 3];
  float4 w0 = *(const float4*)wr;
  float4 w1 = *(const float4*)(wr + 4);
  for (int n = nh * 32; n < nh * 32 + 32; n += 2) {
    const float* hr0 = hc + (size_t)n * H_ + (lane << 3);
    const float* hr1 = hr0 + H_;
    float4 a0 = *(const float4*)hr0;
    float4 a1 = *(const float4*)(hr0 + 4);
    float4 b0 = *(const float4*)hr1;
    float4 b1 = *(const float4*)(hr1 + 4);
    float acc0 = a0.x * w0.x + a0.y * w0.y + a0.z * w0.z + a0.w * w0.w +
                 a1.x * w1.x + a1.y * w1.y + a1.z * w1.z + a1.w * w1.w;
    float acc1 = b0.x * w0.x + b0.y * w0.y + b0.z * w0.z + b0.w * w0.w +
                 b1.x * w1.x + b1.y * w1.y + b1.z * w1.z + b1.w * w1.w;
    acc0 = wred_sum(acc0);
    acc1 = wred_sum(acc1);
    if (lane == 0) {
      hWb[(size_t)n * H_ + h0 + hl] = acc0;
      hWb[(size_t)(n + 1) * H_ + h0 + hl] = acc1;
    }
  }
}

// ---------------------------------------------------------------------------
// valid-position scores.  grid 256 (nb, cb) x 1024; wave per position.
// ---------------------------------------------------------------------------
__global__ __launch_bounds__(1024) void k_scores(
    const int* __restrict__ slens, const float* __restrict__ Vc,
    const float* __restrict__ hWb, const float* __restrict__ vvec,
    float* __restrict__ scores) {
  int nb = blockIdx.x & 63, cb = blockIdx.x >> 6;
  int t = threadIdx.x;
  int len = slens[nb];
  int smax = min(len, W_ - 1);
  int w = t >> 6, lane = t & 63;
  int hb = lane << 3;
  float4 h0 = *(const float4*)(hWb + nb * H_ + hb);
  float4 h1 = *(const float4*)(hWb + nb * H_ + hb + 4);
  float4 v0 = *(const float4*)(vvec + hb);
  float4 v1 = *(const float4*)(vvec + hb + 4);
  int s_end = min((cb + 1) * 128 - 1, smax);
  for (int s = cb * 128 + w; s <= s_end; s += 32) {
    int s2 = s + 16;
    const float* vr = Vc + ((size_t)nb * W_ + s) * H_ + hb;
    float4 x0 = *(const float4*)vr;
    float4 x1 = *(const float4*)(vr + 4);
    float4 y0, y1;
    if (s2 <= s_end) {
      const float* vr2 = Vc + ((size_t)nb * W_ + s2) * H_ + hb;
      y0 = *(const float4*)vr2;
      y1 = *(const float4*)(vr2 + 4);
    }
    float acc;
    acc  = tanh_fast(x0.x + h0.x) * v0.x;
    acc += tanh_fast(x0.y + h0.y) * v0.y;
    acc += tanh_fast(x0.z + h0.z) * v0.z;
    acc += tanh_fast(x0.w + h0.w) * v0.w;
    acc += tanh_fast(x1.x + h1.x) * v1.x;
    acc += tanh_fast(x1.y + h1.y) * v1.y;
    acc += tanh_fast(x1.z + h1.z) * v1.z;
    acc += tanh_fast(x1.w + h1.w) * v1.w;
    acc = wred_sum(acc);
    if (lane == 0) scores[nb * S_ + s] = acc;
    if (s2 <= s_end) {
      float acc2;
      acc2  = tanh_fast(y0.x + h0.x) * v0.x;
      acc2 += tanh_fast(y0.y + h0.y) * v0.y;
      acc2 += tanh_fast(y0.z + h0.z) * v0.z;
      acc2 += tanh_fast(y0.w + h0.w) * v0.w;
      acc2 += tanh_fast(y1.x + h1.x) * v1.x;
      acc2 += tanh_fast(y1.y + h1.y) * v1.y;
      acc2 += tanh_fast(y1.z + h1.z) * v1.z;
      acc2 += tanh_fast(y1.w + h1.w) * v1.w;
      acc2 = wred_sum(acc2);
      if (lane == 0) scores[nb * S_ + s2] = acc2;
    }
  }
  if (cb == 3 && w == 15) {  // appended zero row
    float acc;
    acc  = tanh_fast(h0.x) * v0.x;
    acc += tanh_fast(h0.y) * v0.y;
    acc += tanh_fast(h0.z) * v0.z;
    acc += tanh_fast(h0.w) * v0.w;
    acc += tanh_fast(h1.x) * v1.x;
    acc += tanh_fast(h1.y) * v1.y;
    acc += tanh_fast(h1.z) * v1.z;
    acc += tanh_fast(h1.w) * v1.w;
    acc = wred_sum(acc);
    if (lane == 0) scores[nb * S_ + W_] = acc;
  }
}

// ---------------------------------------------------------------------------
// softmax + beta out + aligned.  grid 256 (nb, cb) x 1024.
// ---------------------------------------------------------------------------
__global__ __launch_bounds__(1024) void k_soft_aligned(
    const float* __restrict__ ctx, const int* __restrict__ slens,
    const float* __restrict__ scores, const float* __restrict__ M0,
    const float* __restrict__ Cmask, float* __restrict__ alignedb,
    float* __restrict__ out, int k) {
  __shared__ float beta[520];
  __shared__ float red[1024];
  __shared__ float4 red4[16 * 64];
  int nb = blockIdx.x & 63, cb = blockIdx.x >> 6;
  int t = threadIdx.x;
  int len = slens[nb];
  int smax = min(len, W_ - 1);
  float m = (t < S_) ? scores[nb * S_ + t] : -3.0e38f;
  red[t] = m;
  __syncthreads();
  for (int st = 512; st > 0; st >>= 1) {
    if (t < st) red[t] = fmaxf(red[t], red[t + st]);
    __syncthreads();
  }
  float M = red[0];
  __syncthreads();
  float e = 0.0f;
  if (t < S_) e = __expf(scores[nb * S_ + t] - M);
  red[t] = e;
  __syncthreads();
  for (int st = 512; st > 0; st >>= 1) {
    if (t < st) red[t] += red[t + st];
    __syncthreads();
  }
  float D = red[0];
  __syncthreads();
  if (t < S_) {
    float bt = e / D;
    beta[t] = bt;
    if (cb == 0) out[(size_t)(nb * KS_ + k) * S_ + t] = bt;
  }
  __syncthreads();
  int dl = t & 63, sl = t >> 6;
  int d4 = cb * 256 + dl * 4;
  const float4* cp = (const float4*)(ctx + (size_t)nb * W_ * TWOH_) + (d4 >> 2);
  float4 acc = make_float4(0.f, 0.f, 0.f, 0.f);
#pragma unroll 8
  for (int s = sl; s <= smax; s += 16) {
    float bt = beta[s];
    float4 c4 = cp[(size_t)s * (TWOH_ / 4)];
    acc.x += bt * c4.x; acc.y += bt * c4.y;
    acc.z += bt * c4.z; acc.w += bt * c4.w;
  }
  red4[sl * 64 + dl] = acc;
  __syncthreads();
  if (sl == 0) {
    float4 s4 = red4[dl];
#pragma unroll
    for (int i = 1; i < 16; ++i) {
      float4 o = red4[i * 64 + dl];
      s4.x += o.x; s4.y += o.y; s4.z += o.z; s4.w += o.w;
    }
    float coef = __expf(M0[nb] - M) / D;
    float4 cm = *(const float4*)(Cmask + nb * TWOH_ + d4);
    s4.x += coef * cm.x; s4.y += coef * cm.y;
    s4.z += coef * cm.z; s4.w += coef * cm.w;
    *(float4*)(alignedb + nb * TWOH_ + d4) = s4;
  }
}

// ---------------------------------------------------------------------------
// GRU cell.  grid 256 x 1024; block owns j0=2b,2b+1; LDS-staged weights.
// ---------------------------------------------------------------------------
__global__ __launch_bounds__(1024) void k_gru(
    const float* __restrict__ alignedb, const float* __restrict__ hc,
    const float* __restrict__ wih, const float* __restrict__ whh,
    const float* __restrict__ bih, const float* __restrict__ bhh,
    float* __restrict__ hnx) {
  __shared__ float ls_wih[6 * TWOH_];
  __shared__ float ls_whh[6 * H_];
  __shared__ float part[8 * 128 * 6];
  int b = blockIdx.x;
  int t = threadIdx.x;
  const int j0 = 2 * b;
  for (int i = t; i < 6 * TWOH_; i += 1024) {
    int row = i >> 10, d = i & 1023;
    int jl = row / 3, g = row - jl * 3;
    ls_wih[i] = wih[(size_t)(g * H_ + j0 + jl) * TWOH_ + d];
  }
  for (int i = t; i < 6 * H_; i += 1024) {
    int row = i >> 9, d = i & 511;
    int jl = row / 3, g = row - jl * 3;
    ls_whh[i] = whh[(size_t)(g * H_ + j0 + jl) * H_ + d];
  }
  __syncthreads();
  int nj = t & 127, sl = t >> 7;
  int n = nj & 63, jl = nj >> 6;
  const float* ar = alignedb + n * TWOH_ + sl * 128;
  const float* hr = hc + n * H_ + sl * 64;
  const float* w0 = ls_wih + (jl * 3 + 0) * TWOH_ + sl * 128;
  const float* w1 = ls_wih + (jl * 3 + 1) * TWOH_ + sl * 128;
  const float* w2 = ls_wih + (jl * 3 + 2) * TWOH_ + sl * 128;
  const float* u0 = ls_whh + (jl * 3 + 0) * H_ + sl * 64;
  const float* u1 = ls_whh + (jl * 3 + 1) * H_ + sl * 64;
  const float* u2 = ls_whh + (jl * 3 + 2) * H_ + sl * 64;
  float g0 = 0.f, g1 = 0.f, g2 = 0.f;
#pragma unroll 8
  for (int i = 0; i < 128; i += 4) {
    float4 a4 = *(const float4*)(ar + i);
    g0 += a4.x * w0[i] + a4.y * w0[i + 1] + a4.z * w0[i + 2] + a4.w * w0[i + 3];
    g1 += a4.x * w1[i] + a4.y * w1[i + 1] + a4.z * w1[i + 2] + a4.w * w1[i + 3];
    g2 += a4.x * w2[i] + a4.y * w2[i + 1] + a4.z * w2[i + 2] + a4.w * w2[i + 3];
  }
  float q0 = 0.f, q1 = 0.f, q2 = 0.f;
#pragma unroll 8
  for (int i = 0; i < 64; i += 4) {
    float4 h4 = *(const float4*)(hr + i);
    q0 += h4.x * u0[i] + h4.y * u0[i + 1] + h4.z * u0[i + 2] + h4.w * u0[i + 3];
    q1 += h4.x * u1[i] + h4.y * u1[i + 1] + h4.z * u1[i + 2] + h4.w * u1[i + 3];
    q2 += h4.x * u2[i] + h4.y * u2[i + 1] + h4.z * u2[i + 2] + h4.w * u2[i + 3];
  }
  float* pp = part + (sl * 128 + nj) * 6;
  pp[0] = g0; pp[1] = g1; pp[2] = g2; pp[3] = q0; pp[4] = q1; pp[5] = q2;
  __syncthreads();
  if (t < 128) {
    int n2 = t & 63, jl2 = t >> 6;
    int j = j0 + jl2;
    float G0 = 0.f, G1 = 0.f, G2 = 0.f, Q0 = 0.f, Q1 = 0.f, Q2 = 0.f;
#pragma unroll
    for (int s = 0; s < 8; ++s) {
      float* p = part + (s * 128 + t) * 6;
      G0 += p[0]; G1 += p[1]; G2 += p[2];
      Q0 += p[3]; Q1 += p[4]; Q2 += p[5];
    }
    float r = sigmoid_f(G0 + bih[j] + Q0 + bhh[j]);
    float z = sigmoid_f(G1 + bih[H_ + j] + Q1 + bhh[H_ + j]);
    float nc = tanh_fast(G2 + bih[2 * H_ + j] + r * (Q2 + bhh[2 * H_ + j]));
    hnx[n2 * H_ + j] = (1.0f - z) * nc + z * hc[n2 * H_ + j];
  }
}

extern "C" void kernel_launch(void* const* d_in, const int* in_sizes, int n_in,
                              void* d_out, int out_size, void* d_ws, size_t ws_size,
                              hipStream_t stream) {
  const float* ctx = (const float*)d_in[0];
  const int* slens = (const int*)d_in[1];
  const float* Vw = (const float*)d_in[3];
  const float* Ww = (const float*)d_in[4];
  const float* vvec = (const float*)d_in[5];
  const float* wih = (const float*)d_in[6];
  const float* whh = (const float*)d_in[7];
  const float* bih = (const float*)d_in[8];
  const float* bhh = (const float*)d_in[9];
  float* out = (float*)d_out;

  float* ws = (float*)d_ws;
  float* Vc = ws;                                   // 64*512*512
  float* scores = Vc + (size_t)N_ * W_ * H_;        // 64*513
  float* M0v = scores + N_ * S_;                    // 64
  float* Cm = M0v + N_;                             // 64*1024
  float* hb = Cm + N_ * TWOH_;                      // 2*64*512
  float* hWb = hb + 2 * N_ * H_;                    // 64*512
  float* al = hWb + N_ * H_;                        // 64*1024

  hipMemsetAsync(hb, 0, (size_t)N_ * H_ * sizeof(float), stream);
  vgemm_f32<<<dim3(8, 512), 256, 0, stream>>>(ctx, Vw, Vc);
  k_prep1<<<64, 1024, 0, stream>>>(ctx, slens, Vw, vvec, Vc, scores, M0v);
  k_prep2<<<256, 1024, 0, stream>>>(ctx, slens, scores, M0v, Cm);

  for (int k = 0; k < KS_; ++k) {
    const float* hc = hb + (k & 1) * (N_ * H_);
    float* hn = hb + ((k + 1) & 1) * (N_ * H_);
    k_hw<<<64, 1024, 0, stream>>>(hc, Ww, hWb);
    k_scores<<<256, 1024, 0, stream>>>(slens, Vc, hWb, vvec, scores);
    k_soft_aligned<<<256, 1024, 0, stream>>>(ctx, slens, scores, M0v, Cm, al,
                                             out, k);
    k_gru<<<256, 1024, 0, stream>>>(al, hc, wih, whh, bih, bhh, hn);
  }
}

// Round 4
// 814.469 us; speedup vs baseline: 3.0420x; 1.3358x over previous
//
#include <hip/hip_runtime.h>

#define N_    64
#define W_    512
#define H_    512
#define S_    513
#define TWOH_ 1024
#define KS_   8

typedef short s16x8 __attribute__((ext_vector_type(8)));
typedef float f32x4 __attribute__((ext_vector_type(4)));

__device__ __forceinline__ float tanh_fast(float x) {
  float xc = fminf(fmaxf(x, -15.0f), 15.0f);
  float e = __expf(2.0f * xc);
  return (e - 1.0f) / (e + 1.0f);
}
__device__ __forceinline__ float sigmoid_f(float x) {
  return 1.0f / (1.0f + __expf(-x));
}
__device__ __forceinline__ float wred_sum(float v) {
#pragma unroll
  for (int m = 32; m > 0; m >>= 1) v += __shfl_xor(v, m, 64);
  return v;
}

__device__ __forceinline__ void gld_lds16(const void* g, void* s) {
  __builtin_amdgcn_global_load_lds((__attribute__((address_space(1))) void*)g,
                                   (__attribute__((address_space(3))) void*)s,
                                   16, 0, 0);
}

// ---------------------------------------------------------------------------
// split-bf16 conversion: hi = bf16_rn(x), lo = bf16_rn(x - hi)
// ---------------------------------------------------------------------------
__global__ __launch_bounds__(256) void k_cvt(const float4* __restrict__ x,
                                             unsigned short* __restrict__ hi,
                                             unsigned short* __restrict__ lo,
                                             int n4) {
  for (int i = blockIdx.x * 256 + threadIdx.x; i < n4; i += gridDim.x * 256) {
    float4 v = x[i];
    float vs[4] = {v.x, v.y, v.z, v.w};
    unsigned short hb[4], lb[4];
#pragma unroll
    for (int j = 0; j < 4; ++j) {
      unsigned u = __float_as_uint(vs[j]);
      unsigned short h = (unsigned short)((u + 0x7FFFu + ((u >> 16) & 1u)) >> 16);
      float hf = __uint_as_float((unsigned)h << 16);
      float lf = vs[j] - hf;
      unsigned u2 = __float_as_uint(lf);
      unsigned short l = (unsigned short)((u2 + 0x7FFFu + ((u2 >> 16) & 1u)) >> 16);
      hb[j] = h; lb[j] = l;
    }
    ushort4 h4; h4.x = hb[0]; h4.y = hb[1]; h4.z = hb[2]; h4.w = hb[3];
    ushort4 l4; l4.x = lb[0]; l4.y = lb[1]; l4.z = lb[2]; l4.w = lb[3];
    ((ushort4*)hi)[i] = h4;
    ((ushort4*)lo)[i] = l4;
  }
}

// ---------------------------------------------------------------------------
// Vc = A * B^T via 3-product split-bf16 MFMA.  A: (32768,1024), B: (512,1024).
// 128x128 tile, BK=32, 4 waves, global_load_lds staging, XCD-chunked swizzle.
// ---------------------------------------------------------------------------
__global__ __launch_bounds__(256, 2) void mfma_gemm(
    const unsigned short* __restrict__ Ahi, const unsigned short* __restrict__ Alo,
    const unsigned short* __restrict__ Bhi, const unsigned short* __restrict__ Blo,
    float* __restrict__ C) {
  __shared__ unsigned short sAh[4096], sAl[4096], sBh[4096], sBl[4096];
  int bid = blockIdx.x;
  int swz = (bid & 7) * 128 + (bid >> 3);  // 1024 wgs, bijective, XCD-chunked
  int mt = swz >> 2, nt = swz & 3;
  int m0 = mt * 128, n0 = nt * 128;
  int tid = threadIdx.x;
  int wave = tid >> 6, lane = tid & 63;
  int wr = wave >> 1, wc = wave & 1;
  int fr = lane & 15, fq = lane >> 4;
  int rA = tid >> 2;           // 0..63
  int cA = (tid & 3) * 8;      // ushort offset in row

  f32x4 acc[4][4] = {};

  const size_t a_row0 = (size_t)(m0 + rA) << 10;
  const size_t a_row1 = (size_t)(m0 + rA + 64) << 10;
  const size_t b_row0 = (size_t)(n0 + rA) << 10;
  const size_t b_row1 = (size_t)(n0 + rA + 64) << 10;
  const int wofs = wave << 9;  // wave-uniform LDS base (ushorts)

  for (int k0 = 0; k0 < 1024; k0 += 32) {
    int off = k0 + cA;
    gld_lds16(Ahi + a_row0 + off, sAh + wofs);
    gld_lds16(Ahi + a_row1 + off, sAh + 2048 + wofs);
    gld_lds16(Alo + a_row0 + off, sAl + wofs);
    gld_lds16(Alo + a_row1 + off, sAl + 2048 + wofs);
    gld_lds16(Bhi + b_row0 + off, sBh + wofs);
    gld_lds16(Bhi + b_row1 + off, sBh + 2048 + wofs);
    gld_lds16(Blo + b_row0 + off, sBl + wofs);
    gld_lds16(Blo + b_row1 + off, sBl + 2048 + wofs);
    __syncthreads();
    s16x8 ah[4], av[4], bh[4], bv[4];
#pragma unroll
    for (int m = 0; m < 4; ++m) {
      int ar = (wr * 64 + m * 16 + fr) * 32 + fq * 8;
      ah[m] = *(const s16x8*)(sAh + ar);
      av[m] = *(const s16x8*)(sAl + ar);
    }
#pragma unroll
    for (int n = 0; n < 4; ++n) {
      int br = (wc * 64 + n * 16 + fr) * 32 + fq * 8;
      bh[n] = *(const s16x8*)(sBh + br);
      bv[n] = *(const s16x8*)(sBl + br);
    }
#pragma unroll
    for (int m = 0; m < 4; ++m)
#pragma unroll
      for (int n = 0; n < 4; ++n) {
        acc[m][n] = __builtin_amdgcn_mfma_f32_16x16x32_bf16(ah[m], bh[n], acc[m][n], 0, 0, 0);
        acc[m][n] = __builtin_amdgcn_mfma_f32_16x16x32_bf16(ah[m], bv[n], acc[m][n], 0, 0, 0);
        acc[m][n] = __builtin_amdgcn_mfma_f32_16x16x32_bf16(av[m], bh[n], acc[m][n], 0, 0, 0);
      }
    __syncthreads();
  }
#pragma unroll
  for (int m = 0; m < 4; ++m) {
    int gr0 = m0 + wr * 64 + m * 16 + fq * 4;
#pragma unroll
    for (int n = 0; n < 4; ++n) {
      int gc = n0 + wc * 64 + n * 16 + fr;
      float* cp = C + (size_t)gr0 * 512 + gc;
#pragma unroll
      for (int r = 0; r < 4; ++r) cp[(size_t)r * 512] = acc[m][n][r];
    }
  }
}

// ---------------------------------------------------------------------------
// fallback fp32 GEMM (used if ws too small for split-bf16 buffers)
// ---------------------------------------------------------------------------
__global__ __launch_bounds__(256) void vgemm_f32(const float* __restrict__ A,
                                                 const float* __restrict__ B,
                                                 float* __restrict__ C) {
  __shared__ float As[32][68];
  __shared__ float Bs[32][68];
  int bx = blockIdx.x;
  int by = blockIdx.y;
  int t = threadIdx.x;
  int tr = t >> 4, tc = t & 15;
  int arow = t >> 3;
  int acol = (t & 7) << 2;
  const float* Ab = A + (size_t)(by * 64) * 1024;
  const float* Bb = B + (size_t)(bx * 64) * 1024;
  float acc[4][4] = {};
  for (int k0 = 0; k0 < 1024; k0 += 32) {
    float4 a0 = *(const float4*)(Ab + (size_t)arow * 1024 + k0 + acol);
    float4 a1 = *(const float4*)(Ab + (size_t)(arow + 32) * 1024 + k0 + acol);
    float4 b0 = *(const float4*)(Bb + (size_t)arow * 1024 + k0 + acol);
    float4 b1 = *(const float4*)(Bb + (size_t)(arow + 32) * 1024 + k0 + acol);
    __syncthreads();
    As[acol + 0][arow] = a0.x; As[acol + 1][arow] = a0.y;
    As[acol + 2][arow] = a0.z; As[acol + 3][arow] = a0.w;
    As[acol + 0][arow + 32] = a1.x; As[acol + 1][arow + 32] = a1.y;
    As[acol + 2][arow + 32] = a1.z; As[acol + 3][arow + 32] = a1.w;
    Bs[acol + 0][arow] = b0.x; Bs[acol + 1][arow] = b0.y;
    Bs[acol + 2][arow] = b0.z; Bs[acol + 3][arow] = b0.w;
    Bs[acol + 0][arow + 32] = b1.x; Bs[acol + 1][arow + 32] = b1.y;
    Bs[acol + 2][arow + 32] = b1.z; Bs[acol + 3][arow + 32] = b1.w;
    __syncthreads();
#pragma unroll
    for (int kk = 0; kk < 32; ++kk) {
      const float4 a4 = *(const float4*)(&As[kk][tr * 4]);
      const float4 b4 = *(const float4*)(&Bs[kk][tc * 4]);
      acc[0][0] += a4.x * b4.x; acc[0][1] += a4.x * b4.y; acc[0][2] += a4.x * b4.z; acc[0][3] += a4.x * b4.w;
      acc[1][0] += a4.y * b4.x; acc[1][1] += a4.y * b4.y; acc[1][2] += a4.y * b4.z; acc[1][3] += a4.y * b4.w;
      acc[2][0] += a4.z * b4.x; acc[2][1] += a4.z * b4.y; acc[2][2] += a4.z * b4.z; acc[2][3] += a4.z * b4.w;
      acc[3][0] += a4.w * b4.x; acc[3][1] += a4.w * b4.y; acc[3][2] += a4.w * b4.z; acc[3][3] += a4.w * b4.w;
    }
  }
  int row0 = by * 64 + tr * 4;
  int col0 = bx * 64 + tc * 4;
#pragma unroll
  for (int i = 0; i < 4; ++i) {
    *(float4*)(C + (size_t)(row0 + i) * 512 + col0) =
        make_float4(acc[i][0], acc[i][1], acc[i][2], acc[i][3]);
  }
}

// ---------------------------------------------------------------------------
// prep1: masked-position scores (step-invariant) + M0[n].  grid 64 x 1024
// ---------------------------------------------------------------------------
__global__ __launch_bounds__(1024) void k_prep1(
    const float* __restrict__ ctx, const int* __restrict__ slens,
    const float* __restrict__ Vw, const float* __restrict__ vvec,
    const float* __restrict__ Vc, float* __restrict__ scores,
    float* __restrict__ M0) {
  __shared__ float red[1024];
  int n = blockIdx.x;
  int t = threadIdx.x;
  int len = slens[n];
  int w = t >> 6, lane = t & 63;
  int hb = lane << 3;
  float4 v0 = *(const float4*)(vvec + hb);
  float4 v1 = *(const float4*)(vvec + hb + 4);
  float vv[8] = {v0.x, v0.y, v0.z, v0.w, v1.x, v1.y, v1.z, v1.w};
  float mymax = -3.0e38f;
  for (int s = len + 1 + w; s < W_; s += 16) {
    const float* vr = Vc + ((size_t)n * W_ + s) * H_ + hb;
    float4 x0 = *(const float4*)vr;
    float4 x1 = *(const float4*)(vr + 4);
    float xs[8] = {x0.x, x0.y, x0.z, x0.w, x1.x, x1.y, x1.z, x1.w};
    float acc = 0.0f;
#pragma unroll
    for (int i = 0; i < 8; ++i) {
      float vcv = xs[i];
      if (fabsf(vcv) < 2e-5f) {  // near-zero dot: fp64 fix-up for true sign
        const float* cr = ctx + ((size_t)n * W_ + s) * TWOH_;
        const float* wr = Vw + (size_t)(hb + i) * TWOH_;
        double dacc = 0.0;
        for (int d = 0; d < TWOH_; ++d) dacc += (double)cr[d] * (double)wr[d];
        vcv = (dacc > 0.0) ? 1.0f : ((dacc < 0.0) ? -1.0f : 0.0f);
      }
      acc += (vcv > 0.0f) ? -vv[i] : ((vcv < 0.0f) ? vv[i] : 0.0f);
    }
    acc = wred_sum(acc);
    if (lane == 0) scores[n * S_ + s] = acc;
    mymax = fmaxf(mymax, acc);
  }
  red[t] = mymax;
  __syncthreads();
  for (int st = 512; st > 0; st >>= 1) {
    if (t < st) red[t] = fmaxf(red[t], red[t + st]);
    __syncthreads();
  }
  if (t == 0) M0[n] = red[0];
}

// ---------------------------------------------------------------------------
// prep2: Cmask[n][d] = sum_masked exp(ms - M0) * (-1e10*ctx).  grid 256 x 1024
// ---------------------------------------------------------------------------
__global__ __launch_bounds__(1024) void k_prep2(
    const float* __restrict__ ctx, const int* __restrict__ slens,
    const float* __restrict__ scores, const float* __restrict__ M0,
    float* __restrict__ Cmask) {
  __shared__ float4 red4[16 * 64];
  int nb = blockIdx.x & 63, cb = blockIdx.x >> 6;
  int t = threadIdx.x;
  int len = slens[nb];
  float m0 = M0[nb];
  int dl = t & 63, sl = t >> 6;
  int d4 = cb * 256 + dl * 4;
  const float4* cp = (const float4*)(ctx + (size_t)nb * W_ * TWOH_) + (d4 >> 2);
  float4 acc = make_float4(0.f, 0.f, 0.f, 0.f);
#pragma unroll 4
  for (int s = len + 1 + sl; s < W_; s += 16) {
    float ew = __expf(scores[nb * S_ + s] - m0);
    float4 c4 = cp[(size_t)s * (TWOH_ / 4)];
    acc.x += ew * c4.x; acc.y += ew * c4.y;
    acc.z += ew * c4.z; acc.w += ew * c4.w;
  }
  red4[sl * 64 + dl] = acc;
  __syncthreads();
  if (sl == 0) {
    float4 s4 = red4[dl];
#pragma unroll
    for (int i = 1; i < 16; ++i) {
      float4 o = red4[i * 64 + dl];
      s4.x += o.x; s4.y += o.y; s4.z += o.z; s4.w += o.w;
    }
    s4.x *= -1.0e10f; s4.y *= -1.0e10f; s4.z *= -1.0e10f; s4.w *= -1.0e10f;
    *(float4*)(Cmask + nb * TWOH_ + d4) = s4;
  }
}

// ---------------------------------------------------------------------------
// hW[n,h] = dot(h[n,:], Ww[h,:]).  grid 64 x 1024; block owns 8 h rows.
// ---------------------------------------------------------------------------
__global__ __launch_bounds__(1024) void k_hw(const float* __restrict__ hc,
                                             const float* __restrict__ Ww,
                                             float* __restrict__ hWb) {
  __shared__ float ww[8][512];
  int b = blockIdx.x;
  int t = threadIdx.x;
  int h0 = b * 8;
  for (int i = t; i < 8 * 512; i += 1024)
    ww[i >> 9][i & 511] = Ww[(size_t)(h0 + (i >> 9)) * H_ + (i & 511)];
  __syncthreads();
  int lane = t & 63;
  int hl = (t >> 6) & 7;
  int nh = t >> 9;
  const float* wr = &ww[hl][lane << 3];
  float4 w0 = *(const float4*)wr;
  float4 w1 = *(const float4*)(wr + 4);
  for (int n = nh * 32; n < nh * 32 + 32; n += 2) {
    const float* hr0 = hc + (size_t)n * H_ + (lane << 3);
    const float* hr1 = hr0 + H_;
    float4 a0 = *(const float4*)hr0;
    float4 a1 = *(const float4*)(hr0 + 4);
    float4 b0 = *(const float4*)hr1;
    float4 b1 = *(const float4*)(hr1 + 4);
    float acc0 = a0.x * w0.x + a0.y * w0.y + a0.z * w0.z + a0.w * w0.w +
                 a1.x * w1.x + a1.y * w1.y + a1.z * w1.z + a1.w * w1.w;
    float acc1 = b0.x * w0.x + b0.y * w0.y + b0.z * w0.z + b0.w * w0.w +
                 b1.x * w1.x + b1.y * w1.y + b1.z * w1.z + b1.w * w1.w;
    acc0 = wred_sum(acc0);
    acc1 = wred_sum(acc1);
    if (lane == 0) {
      hWb[(size_t)n * H_ + h0 + hl] = acc0;
      hWb[(size_t)(n + 1) * H_ + h0 + hl] = acc1;
    }
  }
}

// ---------------------------------------------------------------------------
// valid-position scores.  grid 256 (nb, cb) x 1024; wave per position.
// ---------------------------------------------------------------------------
__global__ __launch_bounds__(1024) void k_scores(
    const int* __restrict__ slens, const float* __restrict__ Vc,
    const float* __restrict__ hWb, const float* __restrict__ vvec,
    float* __restrict__ scores) {
  int nb = blockIdx.x & 63, cb = blockIdx.x >> 6;
  int t = threadIdx.x;
  int len = slens[nb];
  int smax = min(len, W_ - 1);
  int w = t >> 6, lane = t & 63;
  int hb = lane << 3;
  float4 h0 = *(const float4*)(hWb + nb * H_ + hb);
  float4 h1 = *(const float4*)(hWb + nb * H_ + hb + 4);
  float4 v0 = *(const float4*)(vvec + hb);
  float4 v1 = *(const float4*)(vvec + hb + 4);
  int s_end = min((cb + 1) * 128 - 1, smax);
  for (int s = cb * 128 + w; s <= s_end; s += 32) {
    int s2 = s + 16;
    const float* vr = Vc + ((size_t)nb * W_ + s) * H_ + hb;
    float4 x0 = *(const float4*)vr;
    float4 x1 = *(const float4*)(vr + 4);
    float4 y0, y1;
    if (s2 <= s_end) {
      const float* vr2 = Vc + ((size_t)nb * W_ + s2) * H_ + hb;
      y0 = *(const float4*)vr2;
      y1 = *(const float4*)(vr2 + 4);
    }
    float acc;
    acc  = tanh_fast(x0.x + h0.x) * v0.x;
    acc += tanh_fast(x0.y + h0.y) * v0.y;
    acc += tanh_fast(x0.z + h0.z) * v0.z;
    acc += tanh_fast(x0.w + h0.w) * v0.w;
    acc += tanh_fast(x1.x + h1.x) * v1.x;
    acc += tanh_fast(x1.y + h1.y) * v1.y;
    acc += tanh_fast(x1.z + h1.z) * v1.z;
    acc += tanh_fast(x1.w + h1.w) * v1.w;
    acc = wred_sum(acc);
    if (lane == 0) scores[nb * S_ + s] = acc;
    if (s2 <= s_end) {
      float acc2;
      acc2  = tanh_fast(y0.x + h0.x) * v0.x;
      acc2 += tanh_fast(y0.y + h0.y) * v0.y;
      acc2 += tanh_fast(y0.z + h0.z) * v0.z;
      acc2 += tanh_fast(y0.w + h0.w) * v0.w;
      acc2 += tanh_fast(y1.x + h1.x) * v1.x;
      acc2 += tanh_fast(y1.y + h1.y) * v1.y;
      acc2 += tanh_fast(y1.z + h1.z) * v1.z;
      acc2 += tanh_fast(y1.w + h1.w) * v1.w;
      acc2 = wred_sum(acc2);
      if (lane == 0) scores[nb * S_ + s2] = acc2;
    }
  }
  if (cb == 3 && w == 15) {  // appended zero row
    float acc;
    acc  = tanh_fast(h0.x) * v0.x;
    acc += tanh_fast(h0.y) * v0.y;
    acc += tanh_fast(h0.z) * v0.z;
    acc += tanh_fast(h0.w) * v0.w;
    acc += tanh_fast(h1.x) * v1.x;
    acc += tanh_fast(h1.y) * v1.y;
    acc += tanh_fast(h1.z) * v1.z;
    acc += tanh_fast(h1.w) * v1.w;
    acc = wred_sum(acc);
    if (lane == 0) scores[nb * S_ + W_] = acc;
  }
}

// ---------------------------------------------------------------------------
// softmax + beta out + aligned.  grid 256 (nb, cb) x 1024.
// ---------------------------------------------------------------------------
__global__ __launch_bounds__(1024) void k_soft_aligned(
    const float* __restrict__ ctx, const int* __restrict__ slens,
    const float* __restrict__ scores, const float* __restrict__ M0,
    const float* __restrict__ Cmask, float* __restrict__ alignedb,
    float* __restrict__ out, int k) {
  __shared__ float beta[520];
  __shared__ float red[1024];
  __shared__ float4 red4[16 * 64];
  int nb = blockIdx.x & 63, cb = blockIdx.x >> 6;
  int t = threadIdx.x;
  int len = slens[nb];
  int smax = min(len, W_ - 1);
  float m = (t < S_) ? scores[nb * S_ + t] : -3.0e38f;
  red[t] = m;
  __syncthreads();
  for (int st = 512; st > 0; st >>= 1) {
    if (t < st) red[t] = fmaxf(red[t], red[t + st]);
    __syncthreads();
  }
  float M = red[0];
  __syncthreads();
  float e = 0.0f;
  if (t < S_) e = __expf(scores[nb * S_ + t] - M);
  red[t] = e;
  __syncthreads();
  for (int st = 512; st > 0; st >>= 1) {
    if (t < st) red[t] += red[t + st];
    __syncthreads();
  }
  float D = red[0];
  __syncthreads();
  if (t < S_) {
    float bt = e / D;
    beta[t] = bt;
    if (cb == 0) out[(size_t)(nb * KS_ + k) * S_ + t] = bt;
  }
  __syncthreads();
  int dl = t & 63, sl = t >> 6;
  int d4 = cb * 256 + dl * 4;
  const float4* cp = (const float4*)(ctx + (size_t)nb * W_ * TWOH_) + (d4 >> 2);
  float4 acc = make_float4(0.f, 0.f, 0.f, 0.f);
#pragma unroll 8
  for (int s = sl; s <= smax; s += 16) {
    float bt = beta[s];
    float4 c4 = cp[(size_t)s * (TWOH_ / 4)];
    acc.x += bt * c4.x; acc.y += bt * c4.y;
    acc.z += bt * c4.z; acc.w += bt * c4.w;
  }
  red4[sl * 64 + dl] = acc;
  __syncthreads();
  if (sl == 0) {
    float4 s4 = red4[dl];
#pragma unroll
    for (int i = 1; i < 16; ++i) {
      float4 o = red4[i * 64 + dl];
      s4.x += o.x; s4.y += o.y; s4.z += o.z; s4.w += o.w;
    }
    float coef = __expf(M0[nb] - M) / D;
    float4 cm = *(const float4*)(Cmask + nb * TWOH_ + d4);
    s4.x += coef * cm.x; s4.y += coef * cm.y;
    s4.z += coef * cm.z; s4.w += coef * cm.w;
    *(float4*)(alignedb + nb * TWOH_ + d4) = s4;
  }
}

// ---------------------------------------------------------------------------
// GRU cell.  grid 256 x 1024; block owns j0=2b,2b+1; LDS-staged weights.
// ---------------------------------------------------------------------------
__global__ __launch_bounds__(1024) void k_gru(
    const float* __restrict__ alignedb, const float* __restrict__ hc,
    const float* __restrict__ wih, const float* __restrict__ whh,
    const float* __restrict__ bih, const float* __restrict__ bhh,
    float* __restrict__ hnx) {
  __shared__ float ls_wih[6 * TWOH_];
  __shared__ float ls_whh[6 * H_];
  __shared__ float part[8 * 128 * 6];
  int b = blockIdx.x;
  int t = threadIdx.x;
  const int j0 = 2 * b;
  for (int i = t; i < 6 * TWOH_; i += 1024) {
    int row = i >> 10, d = i & 1023;
    int jl = row / 3, g = row - jl * 3;
    ls_wih[i] = wih[(size_t)(g * H_ + j0 + jl) * TWOH_ + d];
  }
  for (int i = t; i < 6 * H_; i += 1024) {
    int row = i >> 9, d = i & 511;
    int jl = row / 3, g = row - jl * 3;
    ls_whh[i] = whh[(size_t)(g * H_ + j0 + jl) * H_ + d];
  }
  __syncthreads();
  int nj = t & 127, sl = t >> 7;
  int n = nj & 63, jl = nj >> 6;
  const float* ar = alignedb + n * TWOH_ + sl * 128;
  const float* hr = hc + n * H_ + sl * 64;
  const float* w0 = ls_wih + (jl * 3 + 0) * TWOH_ + sl * 128;
  const float* w1 = ls_wih + (jl * 3 + 1) * TWOH_ + sl * 128;
  const float* w2 = ls_wih + (jl * 3 + 2) * TWOH_ + sl * 128;
  const float* u0 = ls_whh + (jl * 3 + 0) * H_ + sl * 64;
  const float* u1 = ls_whh + (jl * 3 + 1) * H_ + sl * 64;
  const float* u2 = ls_whh + (jl * 3 + 2) * H_ + sl * 64;
  float g0 = 0.f, g1 = 0.f, g2 = 0.f;
#pragma unroll 8
  for (int i = 0; i < 128; i += 4) {
    float4 a4 = *(const float4*)(ar + i);
    g0 += a4.x * w0[i] + a4.y * w0[i + 1] + a4.z * w0[i + 2] + a4.w * w0[i + 3];
    g1 += a4.x * w1[i] + a4.y * w1[i + 1] + a4.z * w1[i + 2] + a4.w * w1[i + 3];
    g2 += a4.x * w2[i] + a4.y * w2[i + 1] + a4.z * w2[i + 2] + a4.w * w2[i + 3];
  }
  float q0 = 0.f, q1 = 0.f, q2 = 0.f;
#pragma unroll 8
  for (int i = 0; i < 64; i += 4) {
    float4 h4 = *(const float4*)(hr + i);
    q0 += h4.x * u0[i] + h4.y * u0[i + 1] + h4.z * u0[i + 2] + h4.w * u0[i + 3];
    q1 += h4.x * u1[i] + h4.y * u1[i + 1] + h4.z * u1[i + 2] + h4.w * u1[i + 3];
    q2 += h4.x * u2[i] + h4.y * u2[i + 1] + h4.z * u2[i + 2] + h4.w * u2[i + 3];
  }
  float* pp = part + (sl * 128 + nj) * 6;
  pp[0] = g0; pp[1] = g1; pp[2] = g2; pp[3] = q0; pp[4] = q1; pp[5] = q2;
  __syncthreads();
  if (t < 128) {
    int n2 = t & 63, jl2 = t >> 6;
    int j = j0 + jl2;
    float G0 = 0.f, G1 = 0.f, G2 = 0.f, Q0 = 0.f, Q1 = 0.f, Q2 = 0.f;
#pragma unroll
    for (int s = 0; s < 8; ++s) {
      float* p = part + (s * 128 + t) * 6;
      G0 += p[0]; G1 += p[1]; G2 += p[2];
      Q0 += p[3]; Q1 += p[4]; Q2 += p[5];
    }
    float r = sigmoid_f(G0 + bih[j] + Q0 + bhh[j]);
    float z = sigmoid_f(G1 + bih[H_ + j] + Q1 + bhh[H_ + j]);
    float nc = tanh_fast(G2 + bih[2 * H_ + j] + r * (Q2 + bhh[2 * H_ + j]));
    hnx[n2 * H_ + j] = (1.0f - z) * nc + z * hc[n2 * H_ + j];
  }
}

extern "C" void kernel_launch(void* const* d_in, const int* in_sizes, int n_in,
                              void* d_out, int out_size, void* d_ws, size_t ws_size,
                              hipStream_t stream) {
  const float* ctx = (const float*)d_in[0];
  const int* slens = (const int*)d_in[1];
  const float* Vw = (const float*)d_in[3];
  const float* Ww = (const float*)d_in[4];
  const float* vvec = (const float*)d_in[5];
  const float* wih = (const float*)d_in[6];
  const float* whh = (const float*)d_in[7];
  const float* bih = (const float*)d_in[8];
  const float* bhh = (const float*)d_in[9];
  float* out = (float*)d_out;

  float* ws = (float*)d_ws;
  float* Vc = ws;                                   // 64*512*512
  float* scores = Vc + (size_t)N_ * W_ * H_;        // 64*513
  float* M0v = scores + N_ * S_;                    // 64
  float* Cm = M0v + N_;                             // 64*1024
  float* hb = Cm + N_ * TWOH_;                      // 2*64*512
  float* hWb = hb + 2 * N_ * H_;                    // 64*512
  float* al = hWb + N_ * H_;                        // 64*1024
  float* end_f = al + N_ * TWOH_;

  // split-bf16 buffers (beyond the fp32 region)
  unsigned short* Ahi = (unsigned short*)end_f;             // 32768*1024
  unsigned short* Alo = Ahi + (size_t)32768 * 1024;
  unsigned short* Bhi = Alo + (size_t)32768 * 1024;         // 512*1024
  unsigned short* Blo = Bhi + (size_t)512 * 1024;
  size_t need = (size_t)((char*)(Blo + (size_t)512 * 1024) - (char*)d_ws);

  hipMemsetAsync(hb, 0, (size_t)N_ * H_ * sizeof(float), stream);

  if (ws_size >= need) {
    k_cvt<<<2048, 256, 0, stream>>>((const float4*)ctx, Ahi, Alo, 8388608);
    k_cvt<<<512, 256, 0, stream>>>((const float4*)Vw, Bhi, Blo, 131072);
    mfma_gemm<<<1024, 256, 0, stream>>>(Ahi, Alo, Bhi, Blo, Vc);
  } else {
    vgemm_f32<<<dim3(8, 512), 256, 0, stream>>>(ctx, Vw, Vc);
  }

  k_prep1<<<64, 1024, 0, stream>>>(ctx, slens, Vw, vvec, Vc, scores, M0v);
  k_prep2<<<256, 1024, 0, stream>>>(ctx, slens, scores, M0v, Cm);

  for (int k = 0; k < KS_; ++k) {
    const float* hc = hb + (k & 1) * (N_ * H_);
    float* hn = hb + ((k + 1) & 1) * (N_ * H_);
    k_hw<<<64, 1024, 0, stream>>>(hc, Ww, hWb);
    k_scores<<<256, 1024, 0, stream>>>(slens, Vc, hWb, vvec, scores);
    k_soft_aligned<<<256, 1024, 0, stream>>>(ctx, slens, scores, M0v, Cm, al,
                                             out, k);
    k_gru<<<256, 1024, 0, stream>>>(al, hc, wih, whh, bih, bhh, hn);
  }
}